// Round 1
// baseline (1689.395 us; speedup 1.0000x reference)
//
#include <hip/hip_runtime.h>
#include <cstdint>
#include <cstddef>

// ---------- types ----------
typedef __bf16 bf16;
typedef __bf16 bf16x8 __attribute__((ext_vector_type(8)));
typedef float  f32x4  __attribute__((ext_vector_type(4)));

// ---------- problem constants ----------
constexpr int S_      = 2048;
constexpr int H_      = 2048;
constexpr int NH_     = 16;
constexpr int KV_RANK_= 256;
constexpr int EXP_    = 8;
constexpr int INTER_  = 1408;
constexpr int QH_     = 128;   // D_NOPE + D_ROPE
constexpr float EPS_  = 1e-6f;

// ---------- helpers ----------
__device__ inline bf16x8 bzero8() {
  bf16x8 v;
#pragma unroll
  for (int t = 0; t < 8; t++) v[t] = (bf16)0.f;
  return v;
}
__device__ inline bf16x8 loadB8(const bf16* p) { return *(const bf16x8*)p; }
__device__ inline bf16x8 loadB8(const float* p) {
  f32x4 a = *(const f32x4*)p;
  f32x4 b = *(const f32x4*)(p + 4);
  bf16x8 v;
  v[0] = (bf16)a[0]; v[1] = (bf16)a[1]; v[2] = (bf16)a[2]; v[3] = (bf16)a[3];
  v[4] = (bf16)b[0]; v[5] = (bf16)b[1]; v[6] = (bf16)b[2]; v[7] = (bf16)b[3];
  return v;
}

enum { EPI_BF16 = 0, EPI_F32 = 1, EPI_ADD = 2, EPI_SILU = 3, EPI_ACC = 4 };

// ---------------------------------------------------------------------------
// Generic MFMA GEMM: C[M,N] (+)= A[M,K] @ B[N,K]^T
//   A: bf16, row stride K.  B: fp32 (converted to bf16 while staging) or bf16.
//   128x128 tile, BK=32, 256 thr = 4 waves, each wave 64x64 via 4x4 MFMAs.
//   LDS stride 32+8=40 bf16 (80B) -> conflict-free ds_read_b128 (2-way only).
//   Optional z batching (strides zA/zB/zC), causal block skip, per-expert B
//   base for flat-K MoE (kPerE/bExpStride), fused epilogues.
// ---------------------------------------------------------------------------
template <int EPI, typename TB>
__global__ void __launch_bounds__(256, 2) gemm_bt(
    const bf16* __restrict__ A, const TB* __restrict__ B,
    void* __restrict__ Cv, const float* __restrict__ aux,
    int M, int N, int K, int ldc, int causal,
    long zA, long zB, long zC, long auxZ,
    int auxRS, int kPerE, long bExpStride)
{
  if (causal && blockIdx.x > blockIdx.y) return;   // tile fully masked
  const int tileN = blockIdx.x * 128;
  const int tileM = blockIdx.y * 128;
  const int z = blockIdx.z;
  A += (long)z * zA;
  const TB* Bz = B + (long)z * zB;

  __shared__ __align__(16) bf16 As[128][40];
  __shared__ __align__(16) bf16 Bs[128][40];

  const int tid  = threadIdx.x;
  const int lane = tid & 63;
  const int wave = tid >> 6;
  const int wr = wave >> 1, wc = wave & 1;
  const int quad = lane >> 4, r16 = lane & 15;

  f32x4 acc[4][4];
#pragma unroll
  for (int i = 0; i < 4; i++)
#pragma unroll
    for (int j = 0; j < 4; j++)
#pragma unroll
      for (int r = 0; r < 4; r++) acc[i][j][r] = 0.f;

  for (int k0 = 0; k0 < K; k0 += 32) {
    const TB* Bp; int bk, ldb;
    if (kPerE > 0) {            // flat-K MoE: B base hops per expert
      int e = k0 / kPerE;
      Bp = Bz + (long)e * bExpStride;
      bk = k0 - e * kPerE;
      ldb = kPerE;
    } else { Bp = Bz; bk = k0; ldb = K; }

#pragma unroll
    for (int i = 0; i < 2; i++) {
      int el = ((i << 8) + tid) << 3;       // (i*256+tid)*8
      int rr = el >> 5, cc = el & 31;
      int gm = tileM + rr;
      bf16x8 va = (gm < M) ? loadB8(A + (long)gm * K + k0 + cc) : bzero8();
      *(bf16x8*)&As[rr][cc] = va;
      int gn = tileN + rr;
      bf16x8 vb = (gn < N) ? loadB8(Bp + (long)gn * ldb + bk + cc) : bzero8();
      *(bf16x8*)&Bs[rr][cc] = vb;
    }
    __syncthreads();

    bf16x8 af[4], bfv[4];
#pragma unroll
    for (int i = 0; i < 4; i++) af[i]  = *(const bf16x8*)&As[wr * 64 + i * 16 + r16][quad * 8];
#pragma unroll
    for (int j = 0; j < 4; j++) bfv[j] = *(const bf16x8*)&Bs[wc * 64 + j * 16 + r16][quad * 8];
#pragma unroll
    for (int i = 0; i < 4; i++)
#pragma unroll
      for (int j = 0; j < 4; j++)
        acc[i][j] = __builtin_amdgcn_mfma_f32_16x16x32_bf16(af[i], bfv[j], acc[i][j], 0, 0, 0);
    __syncthreads();
  }

  bf16*  Cb = (bf16*)Cv + (long)z * zC;
  float* Cf = (float*)Cv + (long)z * zC;
  const float* auxp = aux + (long)z * auxZ;

  const int mB = tileM + wr * 64 + quad * 4;
  const int nB = tileN + wc * 64 + r16;
#pragma unroll
  for (int i = 0; i < 4; i++) {
#pragma unroll
    for (int r = 0; r < 4; r++) {
      int gm = mB + i * 16 + r;
      if (gm >= M) continue;
      float rowAux = 0.f;
      if constexpr (EPI == EPI_SILU) rowAux = auxp[(long)gm * auxRS];
#pragma unroll
      for (int j = 0; j < 4; j++) {
        int gn = nB + j * 16;
        if (gn >= N) continue;
        float v = acc[i][j][r];
        long off = (long)gm * ldc + gn;
        if constexpr (EPI == EPI_BF16)      Cb[off] = (bf16)v;
        else if constexpr (EPI == EPI_F32)  Cf[off] = v;
        else if constexpr (EPI == EPI_ADD)  Cf[off] = auxp[(long)gm * auxRS + gn] + v;
        else if constexpr (EPI == EPI_SILU) { float s = v / (1.f + __expf(-v)); Cb[off] = (bf16)(s * rowAux); }
        else                                Cf[off] += v;   // EPI_ACC
      }
    }
  }
}

// ---------------------------------------------------------------------------
// RMSNorm: one block per row, NIT*256 cols, fp32 in -> bf16 out
// ---------------------------------------------------------------------------
template <int NIT>
__global__ void __launch_bounds__(256) rmsnorm_k(
    const float* __restrict__ x, const float* __restrict__ w,
    bf16* __restrict__ out, int inStride)
{
  const int row = blockIdx.x, tid = threadIdx.x;
  const float* xr = x + (long)row * inStride;
  float vals[NIT];
  float ss = 0.f;
#pragma unroll
  for (int i = 0; i < NIT; i++) { float v = xr[i * 256 + tid]; vals[i] = v; ss += v * v; }
#pragma unroll
  for (int o = 32; o; o >>= 1) ss += __shfl_xor(ss, o, 64);
  __shared__ float red[4];
  if ((tid & 63) == 0) red[tid >> 6] = ss;
  __syncthreads();
  ss = red[0] + red[1] + red[2] + red[3];
  const float rinv = rsqrtf(ss / (float)(NIT * 256) + EPS_);
  bf16* orow = out + (long)row * (NIT * 256);
#pragma unroll
  for (int i = 0; i < NIT; i++) { int c = i * 256 + tid; orow[c] = (bf16)(w[c] * vals[i] * rinv); }
}

// ---------------------------------------------------------------------------
// RoPE + pack query/key[NH][S][128], V^T[NH][64][S]
// ---------------------------------------------------------------------------
__global__ void prep_qkv_k(const bf16* __restrict__ q, const bf16* __restrict__ kv,
                           const float* __restrict__ ckv, const int* __restrict__ pos,
                           bf16* __restrict__ query, bf16* __restrict__ key,
                           bf16* __restrict__ vvT)
{
  const int s = blockIdx.x, h = blockIdx.y, d = threadIdx.x;
  const long qkOff = ((long)h * S_ + s) * QH_ + d;
  if (d < 64) {
    query[qkOff] = q[(long)s * H_ + h * QH_ + d];
    key[qkOff]   = kv[(long)s * H_ + h * QH_ + d];
    vvT[((long)h * 64 + d) * S_ + s] = kv[(long)s * H_ + h * QH_ + 64 + d];
  } else {
    const int i = d - 64;
    const float p = (float)pos[s];
    const float invf = powf(10000.f, -(float)(2 * (i & 31)) / 64.f);
    const float ang = p * invf;
    const float cc = cosf(ang), sn = sinf(ang);
    const float xq  = (float)q[(long)s * H_ + h * QH_ + 64 + i];
    const float xqr = (i < 32) ? -(float)q[(long)s * H_ + h * QH_ + 64 + i + 32]
                               :  (float)q[(long)s * H_ + h * QH_ + 64 + i - 32];
    query[qkOff] = (bf16)(xq * cc + xqr * sn);
    const float xk  = ckv[(long)s * 320 + 256 + i];
    const float xkr = (i < 32) ? -ckv[(long)s * 320 + 256 + i + 32]
                               :  ckv[(long)s * 320 + 256 + i - 32];
    key[qkOff] = (bf16)(xk * cc + xkr * sn);
  }
}

// ---------------------------------------------------------------------------
// Causal softmax over a [S] row of bf16 scores, in place; masked cols -> 0
// ---------------------------------------------------------------------------
__global__ void __launch_bounds__(256) softmax_causal_k(bf16* __restrict__ sc, long zStride, float scale)
{
  const int row = blockIdx.x, tid = threadIdx.x;
  bf16* p = sc + (long)blockIdx.y * zStride + (long)row * S_;
  float vals[8];
  float mx = -1e30f;
#pragma unroll
  for (int i = 0; i < 8; i++) {
    int c = i * 256 + tid;
    float v = (c <= row) ? (float)p[c] * scale : -1e30f;
    vals[i] = v; mx = fmaxf(mx, v);
  }
#pragma unroll
  for (int o = 32; o; o >>= 1) mx = fmaxf(mx, __shfl_xor(mx, o, 64));
  __shared__ float redA[4], redB[4];
  if ((tid & 63) == 0) redA[tid >> 6] = mx;
  __syncthreads();
  mx = fmaxf(fmaxf(redA[0], redA[1]), fmaxf(redA[2], redA[3]));
  float sum = 0.f;
#pragma unroll
  for (int i = 0; i < 8; i++) { float e = __expf(vals[i] - mx); vals[i] = e; sum += e; }
#pragma unroll
  for (int o = 32; o; o >>= 1) sum += __shfl_xor(sum, o, 64);
  if ((tid & 63) == 0) redB[tid >> 6] = sum;
  __syncthreads();
  sum = redB[0] + redB[1] + redB[2] + redB[3];
  const float rinv = 1.f / sum;
#pragma unroll
  for (int i = 0; i < 8; i++) { int c = i * 256 + tid; p[c] = (bf16)(vals[i] * rinv); }
}

// ---------------------------------------------------------------------------
// Router: logits (8) + softmax per token
// ---------------------------------------------------------------------------
__global__ void __launch_bounds__(256) gate_k(const bf16* __restrict__ mlp,
                                              const float* __restrict__ gw,
                                              float* __restrict__ probs)
{
  const int s = blockIdx.x, tid = threadIdx.x;
  float acc[8];
#pragma unroll
  for (int e = 0; e < 8; e++) acc[e] = 0.f;
  for (int c = tid; c < H_; c += 256) {
    float x = (float)mlp[(long)s * H_ + c];
#pragma unroll
    for (int e = 0; e < 8; e++) acc[e] += x * gw[e * H_ + c];
  }
  __shared__ float red[4][8];
#pragma unroll
  for (int e = 0; e < 8; e++) {
    float v = acc[e];
#pragma unroll
    for (int o = 32; o; o >>= 1) v += __shfl_xor(v, o, 64);
    if ((tid & 63) == 0) red[tid >> 6][e] = v;
  }
  __syncthreads();
  if (tid == 0) {
    float l[8]; float mx = -1e30f;
#pragma unroll
    for (int e = 0; e < 8; e++) { l[e] = red[0][e] + red[1][e] + red[2][e] + red[3][e]; mx = fmaxf(mx, l[e]); }
    float sum = 0.f;
#pragma unroll
    for (int e = 0; e < 8; e++) { l[e] = __expf(l[e] - mx); sum += l[e]; }
    float r = 1.f / sum;
#pragma unroll
    for (int e = 0; e < 8; e++) probs[(long)s * 8 + e] = l[e] * r;
  }
}

__global__ void copy4_k(const float* __restrict__ in, float* __restrict__ out, int n4)
{
  int i = blockIdx.x * 256 + threadIdx.x;
  if (i < n4) ((f32x4*)out)[i] = ((const f32x4*)in)[i];
}

// ---------------------------------------------------------------------------
extern "C" void kernel_launch(void* const* d_in, const int* in_sizes, int n_in,
                              void* d_out, int out_size, void* d_ws, size_t ws_size,
                              hipStream_t stream)
{
  const int*   positions = (const int*)  d_in[0];
  const float* hidden    = (const float*)d_in[1];
  const float* ln1       = (const float*)d_in[2];
  const float* wq        = (const float*)d_in[3];
  const float* wkva      = (const float*)d_in[4];
  const float* lnkv      = (const float*)d_in[5];
  const float* wkvb      = (const float*)d_in[6];
  const float* wo        = (const float*)d_in[7];
  const float* ln2       = (const float*)d_in[8];
  const float* wg        = (const float*)d_in[9];
  const float* wfc1      = (const float*)d_in[10];
  const float* wfc2      = (const float*)d_in[11];
  float* out = (float*)d_out;

  char* wsb = (char*)d_ws;
  size_t off = 0;
  auto alloc = [&](size_t bytes) -> void* {
    void* p = wsb + off;
    off += (bytes + 255) & ~(size_t)255;
    return p;
  };
  bf16*  sa_in = (bf16*) alloc((size_t)S_ * H_ * 2);
  bf16*  qb    = (bf16*) alloc((size_t)S_ * H_ * 2);
  float* ckv   = (float*)alloc((size_t)S_ * 320 * 4);
  bf16*  ckvn  = (bf16*) alloc((size_t)S_ * KV_RANK_ * 2);
  bf16*  kvb   = (bf16*) alloc((size_t)S_ * H_ * 2);
  bf16*  query = (bf16*) alloc((size_t)NH_ * S_ * QH_ * 2);
  bf16*  key   = (bf16*) alloc((size_t)NH_ * S_ * QH_ * 2);
  bf16*  vvT   = (bf16*) alloc((size_t)NH_ * 64 * S_ * 2);
  bf16*  ctx   = (bf16*) alloc((size_t)S_ * NH_ * 64 * 2);
  float* xres  = (float*)alloc((size_t)S_ * H_ * 4);
  bf16*  mlp   = (bf16*) alloc((size_t)S_ * H_ * 2);
  float* probs = (float*)alloc((size_t)S_ * 8 * 4);
  bf16*  hbuf  = (bf16*) alloc((size_t)S_ * EXP_ * INTER_ * 2);
  // scores: all-heads bf16 buffer if ws allows (1 launch-group), else per-head
  const size_t scAll = (size_t)NH_ * S_ * S_ * 2;
  const int nz = (ws_size - off >= scAll + 4096) ? NH_ : 1;
  bf16* scores = (bf16*)alloc((size_t)nz * S_ * S_ * 2);

  const float scale = 0.08838834764831845f;   // 128^-0.5

  rmsnorm_k<8><<<S_, 256, 0, stream>>>(hidden, ln1, sa_in, H_);

  gemm_bt<EPI_BF16, float><<<dim3(16, 16, 1), 256, 0, stream>>>(
      sa_in, wq, qb, hidden, S_, H_, H_, H_, 0, 0, 0, 0, 0, 0, 0, 0);

  gemm_bt<EPI_F32, float><<<dim3(3, 16, 1), 256, 0, stream>>>(
      sa_in, wkva, ckv, hidden, S_, 320, H_, 320, 0, 0, 0, 0, 0, 0, 0, 0);

  rmsnorm_k<1><<<S_, 256, 0, stream>>>(ckv, lnkv, ckvn, 320);

  gemm_bt<EPI_BF16, float><<<dim3(16, 16, 1), 256, 0, stream>>>(
      ckvn, wkvb, kvb, hidden, S_, H_, KV_RANK_, H_, 0, 0, 0, 0, 0, 0, 0, 0);

  prep_qkv_k<<<dim3(S_, NH_), 128, 0, stream>>>(qb, kvb, ckv, positions, query, key, vvT);

  const long zQ = (long)S_ * QH_, zS = (long)S_ * S_, zV = (long)64 * S_;
  for (int l = 0; l < NH_ / nz; l++) {
    gemm_bt<EPI_BF16, bf16><<<dim3(16, 16, nz), 256, 0, stream>>>(
        query + (long)l * nz * zQ, key + (long)l * nz * zQ, scores, hidden,
        S_, S_, QH_, S_, 1, zQ, zQ, zS, 0, 0, 0, 0);
    softmax_causal_k<<<dim3(S_, nz), 256, 0, stream>>>(scores, zS, scale);
    gemm_bt<EPI_BF16, bf16><<<dim3(1, 16, nz), 256, 0, stream>>>(
        scores, vvT + (long)l * nz * zV, ctx + (long)l * nz * 64, hidden,
        S_, 64, S_, NH_ * 64, 0, zS, zV, 64, 0, 0, 0, 0);
  }

  gemm_bt<EPI_ADD, float><<<dim3(16, 16, 1), 256, 0, stream>>>(
      ctx, wo, xres, hidden, S_, H_, NH_ * 64, H_, 0, 0, 0, 0, 0, H_, 0, 0);

  rmsnorm_k<8><<<S_, 256, 0, stream>>>(xres, ln2, mlp, H_);

  gate_k<<<S_, 256, 0, stream>>>(mlp, wg, probs);

  copy4_k<<<(S_ * H_ / 4 + 255) / 256, 256, 0, stream>>>(xres, out, S_ * H_ / 4);

  // fc1 (all 8 experts in z): h[s][e*1408+i] = silu(mlp @ fc1_w[e]^T) * probs[s][e]
  gemm_bt<EPI_SILU, float><<<dim3(11, 16, 8), 256, 0, stream>>>(
      mlp, wfc1, hbuf, probs, S_, INTER_, H_, EXP_ * INTER_, 0,
      0, (long)INTER_ * H_, INTER_, 1, 8, 0, 0);

  // fc2: single flat-K GEMM, K = 8*1408, per-expert B base; accumulate into out(=x)
  gemm_bt<EPI_ACC, float><<<dim3(16, 16, 1), 256, 0, stream>>>(
      hbuf, wfc2, out, hidden, S_, H_, EXP_ * INTER_, H_, 0,
      0, 0, 0, 0, 0, INTER_, (long)H_ * INTER_);
}

// Round 2
// 887.572 us; speedup vs baseline: 1.9034x; 1.9034x over previous
//
#include <hip/hip_runtime.h>
#include <cstdint>
#include <cstddef>

// ---------- types ----------
typedef __bf16 bf16;
typedef __bf16 bf16x8 __attribute__((ext_vector_type(8)));
typedef float  f32x4  __attribute__((ext_vector_type(4)));

// ---------- problem constants ----------
constexpr int S_      = 2048;
constexpr int H_      = 2048;
constexpr int NH_     = 16;
constexpr int KV_RANK_= 256;
constexpr int EXP_    = 8;
constexpr int INTER_  = 1408;
constexpr int QH_     = 128;
constexpr float EPS_  = 1e-6f;

// ---------- async global->LDS (wave-uniform LDS base + lane*16) ----------
__device__ inline void gload16(const void* g, void* l) {
  __builtin_amdgcn_global_load_lds(
      (const __attribute__((address_space(1))) void*)g,
      (__attribute__((address_space(3))) void*)l, 16, 0, 0);
}

enum { EPI_BF16 = 0, EPI_F32 = 1, EPI_ADD = 2, EPI_SILU = 3 };

// ---------------------------------------------------------------------------
// MFMA GEMM: C[M,N] (+)= A[M,K] @ B[N,K]^T
//  A bf16 (lda row stride). B: bf16 or fp32 (TB). 128x128 tile, BK=32,
//  4 waves as 2x2 of 64x64, mfma_f32_16x16x32_bf16.
//  Staging via global_load_lds width=16. LDS layout XOR-swizzled:
//   bf16 tile: chunk(row, slot) at row*64 + slot*16, content colchunk = slot ^ ((row>>1)&3)
//   f32  tile: chunk(row, slot) at row*128 + slot*16, content colchunk = slot ^ (row&7)
//  -> fragment ds_read_b128 hits 8 distinct bank groups (2-way only, free).
//  Flat-K MoE: kPerE>0 walks expert B bases (bExpStride, expBasePerZ per z).
//  B rows are clamped to N-1 (garbage cols discarded in epilogue).
// ---------------------------------------------------------------------------
template <int EPI, typename TB>
__global__ void __launch_bounds__(256) gemm_bt(
    const bf16* __restrict__ A, const TB* __restrict__ B,
    void* __restrict__ Cv, const float* __restrict__ aux,
    int M, int N, int K, int lda, int ldb, int ldc, int causal,
    long zA, long zB, long zC, long auxZ, int auxRS,
    int kPerE, long bExpStride, int expBasePerZ)
{
  if (causal && blockIdx.x > blockIdx.y) return;
  const int tileN = blockIdx.x * 128;
  const int tileM = blockIdx.y * 128;
  const int z = blockIdx.z;
  A += (long)z * zA;

  constexpr int nB = (sizeof(TB) == 4) ? 4 : 2;
  __shared__ __align__(16) bf16 As[128 * 32];
  __shared__ __align__(16) TB  Bs[128 * 32];
  char* AsB = (char*)As;
  char* BsB = (char*)Bs;

  const int tid  = threadIdx.x;
  const int lane = tid & 63;
  const int wave = tid >> 6;
  const int wr = wave >> 1, wc = wave & 1;
  const int quad = lane >> 4, r16 = lane & 15;

  const int ldbe = (kPerE > 0) ? kPerE : ldb;
  const TB* BzBase = (kPerE > 0) ? (B + (long)z * expBasePerZ * bExpStride)
                                 : (B + (long)z * zB);

  // ---- precompute staging addresses (k-invariant parts) ----
  const bf16* aG[2]; char* aL[2];
#pragma unroll
  for (int i = 0; i < 2; i++) {
    int c = ((wave * 2 + i) << 6) + lane;
    int row = c >> 2;
    int cc = ((c & 3) ^ ((row >> 1) & 3)) << 3;      // col element (bf16)
    aG[i] = A + (long)(tileM + row) * lda + cc;
    aL[i] = AsB + ((wave * 2 + i) << 10);
  }
  const TB* bG[nB]; char* bL[nB];
#pragma unroll
  for (int i = 0; i < nB; i++) {
    int c = ((wave * nB + i) << 6) + lane;
    int row, cc;
    if constexpr (sizeof(TB) == 4) { row = c >> 3; cc = ((c & 7) ^ (row & 7)) << 2; }
    else                           { row = c >> 2; cc = ((c & 3) ^ ((row >> 1) & 3)) << 3; }
    int rowg = tileN + row; if (rowg > N - 1) rowg = N - 1;
    bG[i] = BzBase + (long)rowg * ldbe + cc;
    bL[i] = BsB + ((wave * nB + i) << 10);
  }

  f32x4 acc[4][4];
#pragma unroll
  for (int i = 0; i < 4; i++)
#pragma unroll
    for (int j = 0; j < 4; j++)
#pragma unroll
      for (int r = 0; r < 4; r++) acc[i][j][r] = 0.f;

  int bk = 0; long eOff = 0;
  for (int k0 = 0; k0 < K; k0 += 32) {
#pragma unroll
    for (int i = 0; i < 2; i++)  gload16(aG[i] + k0, aL[i]);
#pragma unroll
    for (int i = 0; i < nB; i++) gload16(bG[i] + eOff + bk, bL[i]);
    __syncthreads();

    bf16x8 af[4], bfv[4];
#pragma unroll
    for (int i = 0; i < 4; i++) {
      int row = wr * 64 + i * 16 + r16;
      int slot = quad ^ ((row >> 1) & 3);
      af[i] = *(const bf16x8*)(AsB + row * 64 + slot * 16);
    }
    if constexpr (sizeof(TB) == 2) {
#pragma unroll
      for (int j = 0; j < 4; j++) {
        int row = wc * 64 + j * 16 + r16;
        int slot = quad ^ ((row >> 1) & 3);
        bfv[j] = *(const bf16x8*)(BsB + row * 64 + slot * 16);
      }
    } else {
#pragma unroll
      for (int j = 0; j < 4; j++) {
        int row = wc * 64 + j * 16 + r16;
        int s0 = (quad * 2) ^ (row & 7);
        int s1 = s0 ^ 1;
        f32x4 lo = *(const f32x4*)(BsB + row * 128 + s0 * 16);
        f32x4 hi = *(const f32x4*)(BsB + row * 128 + s1 * 16);
        bf16x8 v;
        v[0] = (bf16)lo[0]; v[1] = (bf16)lo[1]; v[2] = (bf16)lo[2]; v[3] = (bf16)lo[3];
        v[4] = (bf16)hi[0]; v[5] = (bf16)hi[1]; v[6] = (bf16)hi[2]; v[7] = (bf16)hi[3];
        bfv[j] = v;
      }
    }
#pragma unroll
    for (int i = 0; i < 4; i++)
#pragma unroll
      for (int j = 0; j < 4; j++)
        acc[i][j] = __builtin_amdgcn_mfma_f32_16x16x32_bf16(af[i], bfv[j], acc[i][j], 0, 0, 0);
    __syncthreads();

    bk += 32;
    if (kPerE > 0 && bk >= kPerE) { bk = 0; eOff += bExpStride; }
  }

  // ---- epilogue ----
  bf16*  Cb = (bf16*)Cv + (long)z * zC;
  float* Cf = (float*)Cv + (long)z * zC;
  const float* auxp = aux + (long)z * auxZ;
  const int mB = tileM + wr * 64 + quad * 4;
  const int nBs = tileN + wc * 64 + r16;
#pragma unroll
  for (int i = 0; i < 4; i++) {
#pragma unroll
    for (int r = 0; r < 4; r++) {
      int gm = mB + i * 16 + r;
      if (gm >= M) continue;
      float rowAux = 0.f;
      if constexpr (EPI == EPI_SILU) rowAux = auxp[(long)gm * auxRS];
#pragma unroll
      for (int j = 0; j < 4; j++) {
        int gn = nBs + j * 16;
        if (gn >= N) continue;
        float v = acc[i][j][r];
        long off = (long)gm * ldc + gn;
        if constexpr (EPI == EPI_BF16)      Cb[off] = (bf16)v;
        else if constexpr (EPI == EPI_F32)  Cf[off] = v;
        else if constexpr (EPI == EPI_ADD)  Cf[off] = auxp[(long)gm * auxRS + gn] + v;
        else { float s = v / (1.f + __expf(-v)); Cb[off] = (bf16)(s * rowAux); }
      }
    }
  }
}

// ---------------------------------------------------------------------------
template <int NIT>
__global__ void __launch_bounds__(256) rmsnorm_k(
    const float* __restrict__ x, const float* __restrict__ w,
    bf16* __restrict__ out, int inStride)
{
  const int row = blockIdx.x, tid = threadIdx.x;
  const float* xr = x + (long)row * inStride;
  float vals[NIT];
  float ss = 0.f;
#pragma unroll
  for (int i = 0; i < NIT; i++) { float v = xr[i * 256 + tid]; vals[i] = v; ss += v * v; }
#pragma unroll
  for (int o = 32; o; o >>= 1) ss += __shfl_xor(ss, o, 64);
  __shared__ float red[4];
  if ((tid & 63) == 0) red[tid >> 6] = ss;
  __syncthreads();
  ss = red[0] + red[1] + red[2] + red[3];
  const float rinv = rsqrtf(ss / (float)(NIT * 256) + EPS_);
  bf16* orow = out + (long)row * (NIT * 256);
#pragma unroll
  for (int i = 0; i < NIT; i++) { int c = i * 256 + tid; orow[c] = (bf16)(w[c] * vals[i] * rinv); }
}

// ---------------------------------------------------------------------------
__global__ void prep_qkv_k(const bf16* __restrict__ q, const bf16* __restrict__ kv,
                           const float* __restrict__ ckv, const int* __restrict__ pos,
                           bf16* __restrict__ query, bf16* __restrict__ key,
                           bf16* __restrict__ vvT)
{
  const int s = blockIdx.x, h = blockIdx.y, d = threadIdx.x;
  const long qkOff = ((long)h * S_ + s) * QH_ + d;
  if (d < 64) {
    query[qkOff] = q[(long)s * H_ + h * QH_ + d];
    key[qkOff]   = kv[(long)s * H_ + h * QH_ + d];
    vvT[((long)h * 64 + d) * S_ + s] = kv[(long)s * H_ + h * QH_ + 64 + d];
  } else {
    const int i = d - 64;
    const float p = (float)pos[s];
    const float invf = powf(10000.f, -(float)(2 * (i & 31)) / 64.f);
    const float ang = p * invf;
    const float cc = cosf(ang), sn = sinf(ang);
    const float xq  = (float)q[(long)s * H_ + h * QH_ + 64 + i];
    const float xqr = (i < 32) ? -(float)q[(long)s * H_ + h * QH_ + 64 + i + 32]
                               :  (float)q[(long)s * H_ + h * QH_ + 64 + i - 32];
    query[qkOff] = (bf16)(xq * cc + xqr * sn);
    const float xk  = ckv[(long)s * 320 + 256 + i];
    const float xkr = (i < 32) ? -ckv[(long)s * 320 + 256 + i + 32]
                               :  ckv[(long)s * 320 + 256 + i - 32];
    key[qkOff] = (bf16)(xk * cc + xkr * sn);
  }
}

// ---------------------------------------------------------------------------
__global__ void __launch_bounds__(256) softmax_causal_k(bf16* __restrict__ sc, long zStride, float scale)
{
  const int row = blockIdx.x, tid = threadIdx.x;
  bf16* p = sc + (long)blockIdx.y * zStride + (long)row * S_;
  float vals[8];
  float mx = -1e30f;
#pragma unroll
  for (int i = 0; i < 8; i++) {
    int c = i * 256 + tid;
    float v = (c <= row) ? (float)p[c] * scale : -1e30f;
    vals[i] = v; mx = fmaxf(mx, v);
  }
#pragma unroll
  for (int o = 32; o; o >>= 1) mx = fmaxf(mx, __shfl_xor(mx, o, 64));
  __shared__ float redA[4], redB[4];
  if ((tid & 63) == 0) redA[tid >> 6] = mx;
  __syncthreads();
  mx = fmaxf(fmaxf(redA[0], redA[1]), fmaxf(redA[2], redA[3]));
  float sum = 0.f;
#pragma unroll
  for (int i = 0; i < 8; i++) { float e = __expf(vals[i] - mx); vals[i] = e; sum += e; }
#pragma unroll
  for (int o = 32; o; o >>= 1) sum += __shfl_xor(sum, o, 64);
  if ((tid & 63) == 0) redB[tid >> 6] = sum;
  __syncthreads();
  sum = redB[0] + redB[1] + redB[2] + redB[3];
  const float rinv = 1.f / sum;
#pragma unroll
  for (int i = 0; i < 8; i++) { int c = i * 256 + tid; p[c] = (bf16)(vals[i] * rinv); }
}

// ---------------------------------------------------------------------------
__global__ void __launch_bounds__(256) gate_k(const bf16* __restrict__ mlp,
                                              const float* __restrict__ gw,
                                              float* __restrict__ probs)
{
  const int s = blockIdx.x, tid = threadIdx.x;
  float acc[8];
#pragma unroll
  for (int e = 0; e < 8; e++) acc[e] = 0.f;
  for (int c = tid; c < H_; c += 256) {
    float x = (float)mlp[(long)s * H_ + c];
#pragma unroll
    for (int e = 0; e < 8; e++) acc[e] += x * gw[e * H_ + c];
  }
  __shared__ float red[4][8];
#pragma unroll
  for (int e = 0; e < 8; e++) {
    float v = acc[e];
#pragma unroll
    for (int o = 32; o; o >>= 1) v += __shfl_xor(v, o, 64);
    if ((tid & 63) == 0) red[tid >> 6][e] = v;
  }
  __syncthreads();
  if (tid == 0) {
    float l[8]; float mx = -1e30f;
#pragma unroll
    for (int e = 0; e < 8; e++) { l[e] = red[0][e] + red[1][e] + red[2][e] + red[3][e]; mx = fmaxf(mx, l[e]); }
    float sum = 0.f;
#pragma unroll
    for (int e = 0; e < 8; e++) { l[e] = __expf(l[e] - mx); sum += l[e]; }
    float r = 1.f / sum;
#pragma unroll
    for (int e = 0; e < 8; e++) probs[(long)s * 8 + e] = l[e] * r;
  }
}

// ---------------------------------------------------------------------------
__global__ void __launch_bounds__(256) wconv_k(const float* __restrict__ in,
                                               bf16* __restrict__ out, int n8)
{
  int i = blockIdx.x * 256 + threadIdx.x;
  if (i < n8) {
    f32x4 a = ((const f32x4*)in)[2 * i];
    f32x4 b = ((const f32x4*)in)[2 * i + 1];
    bf16x8 v;
    v[0] = (bf16)a[0]; v[1] = (bf16)a[1]; v[2] = (bf16)a[2]; v[3] = (bf16)a[3];
    v[4] = (bf16)b[0]; v[5] = (bf16)b[1]; v[6] = (bf16)b[2]; v[7] = (bf16)b[3];
    ((bf16x8*)out)[i] = v;
  }
}

__global__ void __launch_bounds__(256) reduce_out_k(
    const float* __restrict__ xres, const float* __restrict__ parts,
    float* __restrict__ out, int n4, int nz, long zStride4)
{
  int i = blockIdx.x * 256 + threadIdx.x;
  if (i < n4) {
    f32x4 v = ((const f32x4*)xres)[i];
    for (int zz = 0; zz < nz; zz++) v += ((const f32x4*)parts)[(long)zz * zStride4 + i];
    ((f32x4*)out)[i] = v;
  }
}

// ---------------------------------------------------------------------------
extern "C" void kernel_launch(void* const* d_in, const int* in_sizes, int n_in,
                              void* d_out, int out_size, void* d_ws, size_t ws_size,
                              hipStream_t stream)
{
  const int*   positions = (const int*)  d_in[0];
  const float* hidden    = (const float*)d_in[1];
  const float* ln1       = (const float*)d_in[2];
  const float* wq        = (const float*)d_in[3];
  const float* wkva      = (const float*)d_in[4];
  const float* lnkv      = (const float*)d_in[5];
  const float* wkvb      = (const float*)d_in[6];
  const float* wo        = (const float*)d_in[7];
  const float* ln2       = (const float*)d_in[8];
  const float* wg        = (const float*)d_in[9];
  const float* wfc1      = (const float*)d_in[10];
  const float* wfc2      = (const float*)d_in[11];
  float* out = (float*)d_out;

  char* wsb = (char*)d_ws;
  size_t off = 0;
  auto alloc = [&](size_t bytes) -> void* {
    void* p = wsb + off;
    off += (bytes + 255) & ~(size_t)255;
    return p;
  };
  bf16*  sa_in = (bf16*) alloc((size_t)S_ * H_ * 2);
  bf16*  qb    = (bf16*) alloc((size_t)S_ * H_ * 2);
  float* ckv   = (float*)alloc((size_t)S_ * 320 * 4);
  bf16*  ckvn  = (bf16*) alloc((size_t)S_ * KV_RANK_ * 2);
  bf16*  kvb   = (bf16*) alloc((size_t)S_ * H_ * 2);
  bf16*  query = (bf16*) alloc((size_t)NH_ * S_ * QH_ * 2);
  bf16*  key   = (bf16*) alloc((size_t)NH_ * S_ * QH_ * 2);
  bf16*  vvT   = (bf16*) alloc((size_t)NH_ * 64 * S_ * 2);
  bf16*  ctx   = (bf16*) alloc((size_t)S_ * NH_ * 64 * 2);
  float* xres  = (float*)alloc((size_t)S_ * H_ * 4);
  bf16*  mlp   = (bf16*) alloc((size_t)S_ * H_ * 2);
  float* probs = (float*)alloc((size_t)S_ * 8 * 4);
  bf16*  hbuf  = (bf16*) alloc((size_t)S_ * EXP_ * INTER_ * 2);

  const size_t MBy = (size_t)1 << 20;
  const size_t rem = (ws_size > off) ? ws_size - off : 0;
  const size_t szAttnW = ((size_t)H_*H_ + 320*H_ + (size_t)H_*KV_RANK_ + (size_t)H_*NH_*64) * 2;
  const size_t szMoeW1 = (size_t)EXP_ * INTER_ * H_ * 2;   // 46.1 MB each
  const size_t szSS    = (size_t)S_ * S_ * 2;              // 8.39 MB per head
  const size_t szPart  = (size_t)S_ * H_ * 4;              // 16.78 MB per z

  int tier;
  if      (rem >= 312 * MBy) tier = 1;
  else if (rem >= 152 * MBy) tier = 2;
  else                       tier = 3;

  bf16 *wqb = nullptr, *wkvab = nullptr, *wkvbb = nullptr, *wob = nullptr;
  bf16 *fc1b = nullptr, *fc2b = nullptr;
  float* parts; bf16* scores;
  int nz, zsplit;
  if (tier == 1) {
    wqb   = (bf16*)alloc((size_t)H_ * H_ * 2);
    wkvab = (bf16*)alloc((size_t)320 * H_ * 2);
    wkvbb = (bf16*)alloc((size_t)H_ * KV_RANK_ * 2);
    wob   = (bf16*)alloc((size_t)H_ * NH_ * 64 * 2);
    fc1b  = (bf16*)alloc(szMoeW1);
    fc2b  = (bf16*)alloc(szMoeW1);
    parts  = (float*)alloc(4 * szPart);
    scores = (bf16*) alloc(16 * szSS);
    nz = 16; zsplit = 4;
  } else if (tier == 2) {
    wqb   = (bf16*)alloc((size_t)H_ * H_ * 2);
    wkvab = (bf16*)alloc((size_t)320 * H_ * 2);
    wkvbb = (bf16*)alloc((size_t)H_ * KV_RANK_ * 2);
    wob   = (bf16*)alloc((size_t)H_ * NH_ * 64 * 2);
    char* U = (char*)alloc(16 * szSS);     // 134 MB union region
    scores = (bf16*)U; nz = 16;
    fc1b = (bf16*)U;                        // written after scores is dead
    fc2b = (bf16*)(U + szMoeW1);
    parts = (float*)(U + 2 * szMoeW1);      // 33.6 MB fits in remaining 41.9
    zsplit = 2;
  } else {
    char* U = (char*)alloc(2 * szPart);     // 33.6 MB union region
    scores = (bf16*)U; nz = 1;              // scores dead before fc2 writes parts
    parts = (float*)U;
    zsplit = 2;
  }
  const bool cw = (tier <= 2);

  const float scale = 0.08838834764831845f;   // 128^-0.5

  rmsnorm_k<8><<<S_, 256, 0, stream>>>(hidden, ln1, sa_in, H_);

  if (cw) {
    wconv_k<<<(H_*H_/8 + 255)/256, 256, 0, stream>>>(wq, wqb, H_*H_/8);
    wconv_k<<<(320*H_/8 + 255)/256, 256, 0, stream>>>(wkva, wkvab, 320*H_/8);
    wconv_k<<<(H_*KV_RANK_/8 + 255)/256, 256, 0, stream>>>(wkvb, wkvbb, H_*KV_RANK_/8);
    wconv_k<<<(H_*NH_*64/8 + 255)/256, 256, 0, stream>>>(wo, wob, H_*NH_*64/8);
  }

  // q_proj: [2048,2048] = sa_in @ wq^T
  if (cw) gemm_bt<EPI_BF16, bf16><<<dim3(16,16,1), 256, 0, stream>>>(
      sa_in, wqb, qb, hidden, S_, H_, H_, H_, H_, H_, 0, 0,0,0,0, 0, 0,0,0);
  else    gemm_bt<EPI_BF16, float><<<dim3(16,16,1), 256, 0, stream>>>(
      sa_in, wq,  qb, hidden, S_, H_, H_, H_, H_, H_, 0, 0,0,0,0, 0, 0,0,0);

  // kv_a: [2048,320]
  if (cw) gemm_bt<EPI_F32, bf16><<<dim3(3,16,1), 256, 0, stream>>>(
      sa_in, wkvab, ckv, hidden, S_, 320, H_, H_, H_, 320, 0, 0,0,0,0, 0, 0,0,0);
  else    gemm_bt<EPI_F32, float><<<dim3(3,16,1), 256, 0, stream>>>(
      sa_in, wkva,  ckv, hidden, S_, 320, H_, H_, H_, 320, 0, 0,0,0,0, 0, 0,0,0);

  rmsnorm_k<1><<<S_, 256, 0, stream>>>(ckv, lnkv, ckvn, 320);

  // kv_b: [2048,2048], K=256
  if (cw) gemm_bt<EPI_BF16, bf16><<<dim3(16,16,1), 256, 0, stream>>>(
      ckvn, wkvbb, kvb, hidden, S_, H_, KV_RANK_, KV_RANK_, KV_RANK_, H_, 0, 0,0,0,0, 0, 0,0,0);
  else    gemm_bt<EPI_BF16, float><<<dim3(16,16,1), 256, 0, stream>>>(
      ckvn, wkvb,  kvb, hidden, S_, H_, KV_RANK_, KV_RANK_, KV_RANK_, H_, 0, 0,0,0,0, 0, 0,0,0);

  prep_qkv_k<<<dim3(S_, NH_), 128, 0, stream>>>(qb, kvb, ckv, positions, query, key, vvT);

  const long zQ = (long)S_ * QH_, zS = (long)S_ * S_, zV = (long)64 * S_;
  for (int l = 0; l < NH_ / nz; l++) {
    gemm_bt<EPI_BF16, bf16><<<dim3(16,16,nz), 256, 0, stream>>>(
        query + (long)l*nz*zQ, key + (long)l*nz*zQ, scores, hidden,
        S_, S_, QH_, QH_, QH_, S_, 1, zQ, zQ, zS, 0, 0, 0,0,0);
    softmax_causal_k<<<dim3(S_, nz), 256, 0, stream>>>(scores, zS, scale);
    gemm_bt<EPI_BF16, bf16><<<dim3(1,16,nz), 256, 0, stream>>>(
        scores, vvT + (long)l*nz*zV, ctx + (long)l*nz*64, hidden,
        S_, 64, S_, S_, S_, NH_*64, 0, zS, zV, 64, 0, 0, 0,0,0);
  }

  // MoE weight conversion (scores region is dead now in tier 2)
  if (cw) {
    wconv_k<<<(EXP_*INTER_*H_/8 + 255)/256, 256, 0, stream>>>(wfc1, fc1b, EXP_*INTER_*H_/8);
    wconv_k<<<(EXP_*INTER_*H_/8 + 255)/256, 256, 0, stream>>>(wfc2, fc2b, EXP_*INTER_*H_/8);
  }

  // o_proj: xres = hidden + ctx @ wo^T
  if (cw) gemm_bt<EPI_ADD, bf16><<<dim3(16,16,1), 256, 0, stream>>>(
      ctx, wob, xres, hidden, S_, H_, NH_*64, NH_*64, NH_*64, H_, 0, 0,0,0,0, H_, 0,0,0);
  else    gemm_bt<EPI_ADD, float><<<dim3(16,16,1), 256, 0, stream>>>(
      ctx, wo,  xres, hidden, S_, H_, NH_*64, NH_*64, NH_*64, H_, 0, 0,0,0,0, H_, 0,0,0);

  rmsnorm_k<8><<<S_, 256, 0, stream>>>(xres, ln2, mlp, H_);
  gate_k<<<S_, 256, 0, stream>>>(mlp, wg, probs);

  // fc1: h[s][e*1408+i] = silu(mlp @ fc1_w[e]^T) * probs[s][e]
  if (cw) gemm_bt<EPI_SILU, bf16><<<dim3(11,16,8), 256, 0, stream>>>(
      mlp, fc1b, hbuf, probs, S_, INTER_, H_, H_, H_, EXP_*INTER_, 0,
      0, (long)INTER_*H_, INTER_, 1, 8, 0, 0, 0);
  else    gemm_bt<EPI_SILU, float><<<dim3(11,16,8), 256, 0, stream>>>(
      mlp, wfc1, hbuf, probs, S_, INTER_, H_, H_, H_, EXP_*INTER_, 0,
      0, (long)INTER_*H_, INTER_, 1, 8, 0, 0, 0);

  // fc2: split-K over experts -> fp32 partials
  const int Kz = EXP_ * INTER_ / zsplit;
  const int expPerZ = EXP_ / zsplit;
  if (cw) gemm_bt<EPI_F32, bf16><<<dim3(16,16,zsplit), 256, 0, stream>>>(
      hbuf, fc2b, parts, hidden, S_, H_, Kz, EXP_*INTER_, 0, H_, 0,
      Kz, 0, (long)S_*H_, 0, 0, INTER_, (long)H_*INTER_, expPerZ);
  else    gemm_bt<EPI_F32, float><<<dim3(16,16,zsplit), 256, 0, stream>>>(
      hbuf, wfc2, parts, hidden, S_, H_, Kz, EXP_*INTER_, 0, H_, 0,
      Kz, 0, (long)S_*H_, 0, 0, INTER_, (long)H_*INTER_, expPerZ);

  reduce_out_k<<<(S_*H_/4 + 255)/256, 256, 0, stream>>>(
      xres, parts, out, S_*H_/4, zsplit, (long)S_*H_/4);
}

// Round 3
// 790.632 us; speedup vs baseline: 2.1368x; 1.1226x over previous
//
#include <hip/hip_runtime.h>
#include <cstdint>
#include <cstddef>

typedef __bf16 bf16;
typedef __bf16 bf16x8 __attribute__((ext_vector_type(8)));
typedef float  f32x4  __attribute__((ext_vector_type(4)));

constexpr int S_      = 2048;
constexpr int H_      = 2048;
constexpr int NH_     = 16;
constexpr int KV_RANK_= 256;
constexpr int EXP_    = 8;
constexpr int INTER_  = 1408;
constexpr int QH_     = 128;
constexpr float EPS_  = 1e-6f;

__device__ inline void gload16(const void* g, void* l) {
  __builtin_amdgcn_global_load_lds(
      (const __attribute__((address_space(1))) void*)g,
      (__attribute__((address_space(3))) void*)l, 16, 0, 0);
}

enum { EPI_BF16 = 0, EPI_F32 = 1, EPI_ADD = 2, EPI_SILU = 3, EPI_ATOM = 4 };

// ---------------------------------------------------------------------------
// MFMA GEMM: C[M,N] (+)= A[M,K] @ B[N,K]^T   (BK=64, TILE in {64,128})
//  A bf16. B bf16 or fp32 (converted after LDS read). 4 waves as 2x2, each
//  wave (TILE/2)^2 via FRxFRx2 mfma_f32_16x16x32_bf16.
//  LDS rows: bf16 = 64 elem/128B (8 chunks), f32 = 64 elem/256B (16 chunks).
//  XOR swizzle: bf16 slot = chunk ^ (row&7); f32 slot = chunk ^ (row&15).
//  flags: bit0 = causal tile skip (scores), bit1 = K-causal limit (PV).
//  kPerE>0: flat-K MoE, B base hops every kPerE cols by bExpStride.
// ---------------------------------------------------------------------------
template <int EPI, typename TB, int TILE>
__global__ void __launch_bounds__(256) gemm_bt(
    const bf16* __restrict__ A, const TB* __restrict__ B,
    void* __restrict__ Cv, const float* __restrict__ aux,
    int M, int N, int K, int lda, int ldb, int ldc, int flags,
    long zA, long zB, long zC, long auxZ, int auxRS,
    int kPerE, long bExpStride, int expBasePerZ)
{
  constexpr int FR = TILE / 32;         // 16x16 frags per wave dim
  if ((flags & 1) && blockIdx.x > blockIdx.y) return;
  const int tileN = blockIdx.x * TILE;
  const int tileM = blockIdx.y * TILE;
  const int z = blockIdx.z;
  A += (long)z * zA;

  __shared__ __align__(16) bf16 As[TILE * 64];
  __shared__ __align__(16) TB   Bs[TILE * 64];
  char* AsB = (char*)As;
  char* BsB = (char*)Bs;

  const int tid  = threadIdx.x;
  const int lane = tid & 63;
  const int wave = tid >> 6;
  const int wr = wave >> 1, wc = wave & 1;
  const int quad = lane >> 4, r16 = lane & 15;

  const int ldbe = (kPerE > 0) ? kPerE : ldb;
  const TB* BzBase = (kPerE > 0) ? (B + (long)z * expBasePerZ * bExpStride)
                                 : (B + (long)z * zB);

  // ---- staging addresses (k-invariant) ----
  constexpr int IA = TILE / 32;                       // A issues per wave
  const bf16* aG[IA]; char* aL[IA];
#pragma unroll
  for (int i = 0; i < IA; i++) {
    int n = (wave * IA + i) * 64 + lane;
    int row = n >> 3, cp = n & 7;
    int cc = (cp ^ (row & 7)) << 3;                   // col element
    int rowg = tileM + row; if (rowg > M - 1) rowg = M - 1;
    aG[i] = A + (long)rowg * lda + cc;
    aL[i] = AsB + (long)(wave * IA + i) * 1024;
  }
  constexpr int IB = (sizeof(TB) == 4) ? (TILE / 16) : (TILE / 32);
  const TB* bG[IB]; char* bL[IB];
#pragma unroll
  for (int i = 0; i < IB; i++) {
    int n = (wave * IB + i) * 64 + lane;
    int row, cc;
    if constexpr (sizeof(TB) == 4) { row = n >> 4; cc = ((n & 15) ^ (row & 15)) << 2; }
    else                           { row = n >> 3; cc = ((n & 7)  ^ (row & 7))  << 3; }
    int rowg = tileN + row; if (rowg > N - 1) rowg = N - 1;
    bG[i] = BzBase + (long)rowg * ldbe + cc;
    bL[i] = BsB + (long)(wave * IB + i) * 1024;
  }

  // ---- fragment LDS offsets (k-invariant) ----
  int aOff[FR], bOff[FR];
#pragma unroll
  for (int i = 0; i < FR; i++) {
    int row = wr * (TILE / 2) + i * 16 + r16;
    aOff[i] = row * 128 + ((quad ^ (row & 7)) << 4);
  }
#pragma unroll
  for (int j = 0; j < FR; j++) {
    int row = wc * (TILE / 2) + j * 16 + r16;
    if constexpr (sizeof(TB) == 4) bOff[j] = row * 256 + (((2 * quad) ^ (row & 15)) << 4);
    else                           bOff[j] = row * 128 + ((quad ^ (row & 7)) << 4);
  }

  f32x4 acc[FR][FR];
#pragma unroll
  for (int i = 0; i < FR; i++)
#pragma unroll
    for (int j = 0; j < FR; j++)
#pragma unroll
      for (int r = 0; r < 4; r++) acc[i][j][r] = 0.f;

  const int kEnd = (flags & 2) ? (tileM + TILE < K ? tileM + TILE : K) : K;
  int bk = 0; long eOff = 0;
  for (int k0 = 0; k0 < kEnd; k0 += 64) {
#pragma unroll
    for (int i = 0; i < IA; i++) gload16(aG[i] + k0, aL[i]);
#pragma unroll
    for (int i = 0; i < IB; i++) gload16(bG[i] + eOff + bk, bL[i]);
    __syncthreads();

#pragma unroll
    for (int s = 0; s < 2; s++) {
      bf16x8 af[FR], bfv[FR];
#pragma unroll
      for (int i = 0; i < FR; i++)
        af[i] = *(const bf16x8*)(AsB + (aOff[i] ^ (s << 6)));
#pragma unroll
      for (int j = 0; j < FR; j++) {
        if constexpr (sizeof(TB) == 2) {
          bfv[j] = *(const bf16x8*)(BsB + (bOff[j] ^ (s << 6)));
        } else {
          int a0 = bOff[j] ^ (s << 7);
          f32x4 lo = *(const f32x4*)(BsB + a0);
          f32x4 hi = *(const f32x4*)(BsB + (a0 ^ 16));
          bf16x8 v;
          v[0]=(bf16)lo[0]; v[1]=(bf16)lo[1]; v[2]=(bf16)lo[2]; v[3]=(bf16)lo[3];
          v[4]=(bf16)hi[0]; v[5]=(bf16)hi[1]; v[6]=(bf16)hi[2]; v[7]=(bf16)hi[3];
          bfv[j] = v;
        }
      }
#pragma unroll
      for (int i = 0; i < FR; i++)
#pragma unroll
        for (int j = 0; j < FR; j++)
          acc[i][j] = __builtin_amdgcn_mfma_f32_16x16x32_bf16(af[i], bfv[j], acc[i][j], 0, 0, 0);
    }
    __syncthreads();

    bk += 64;
    if (kPerE > 0 && bk >= kPerE) { bk = 0; eOff += bExpStride; }
  }

  // ---- epilogue ----
  bf16*  Cb = (bf16*)Cv + (long)z * zC;
  float* Cf = (float*)Cv + (long)z * zC;
  const float* auxp = aux + (long)z * auxZ;
  const int mB = tileM + wr * (TILE / 2) + quad * 4;
  const int nB = tileN + wc * (TILE / 2) + r16;
#pragma unroll
  for (int i = 0; i < FR; i++) {
#pragma unroll
    for (int r = 0; r < 4; r++) {
      int gm = mB + i * 16 + r;
      if (gm >= M) continue;
      float rowAux = 0.f;
      if constexpr (EPI == EPI_SILU) rowAux = auxp[(long)gm * auxRS];
#pragma unroll
      for (int j = 0; j < FR; j++) {
        int gn = nB + j * 16;
        if (gn >= N) continue;
        float v = acc[i][j][r];
        long off = (long)gm * ldc + gn;
        if constexpr (EPI == EPI_BF16)      Cb[off] = (bf16)v;
        else if constexpr (EPI == EPI_F32)  Cf[off] = v;
        else if constexpr (EPI == EPI_ADD)  Cf[off] = auxp[(long)gm * auxRS + gn] + v;
        else if constexpr (EPI == EPI_SILU) { float sv = v / (1.f + __expf(-v)); Cb[off] = (bf16)(sv * rowAux); }
        else                                atomicAdd(&Cf[off], v);   // EPI_ATOM
      }
    }
  }
}

// ---------------------------------------------------------------------------
template <int NIT>
__global__ void __launch_bounds__(256) rmsnorm_k(
    const float* __restrict__ x, const float* __restrict__ w,
    bf16* __restrict__ out, int inStride)
{
  const int row = blockIdx.x, tid = threadIdx.x;
  const float* xr = x + (long)row * inStride;
  float vals[NIT];
  float ss = 0.f;
#pragma unroll
  for (int i = 0; i < NIT; i++) { float v = xr[i * 256 + tid]; vals[i] = v; ss += v * v; }
#pragma unroll
  for (int o = 32; o; o >>= 1) ss += __shfl_xor(ss, o, 64);
  __shared__ float red[4];
  if ((tid & 63) == 0) red[tid >> 6] = ss;
  __syncthreads();
  ss = red[0] + red[1] + red[2] + red[3];
  const float rinv = rsqrtf(ss / (float)(NIT * 256) + EPS_);
  bf16* orow = out + (long)row * (NIT * 256);
#pragma unroll
  for (int i = 0; i < NIT; i++) { int c = i * 256 + tid; orow[c] = (bf16)(w[c] * vals[i] * rinv); }
}

// ---------------------------------------------------------------------------
__global__ void prep_qkv_k(const bf16* __restrict__ q, const bf16* __restrict__ kv,
                           const float* __restrict__ ckv, const int* __restrict__ pos,
                           bf16* __restrict__ query, bf16* __restrict__ key,
                           bf16* __restrict__ vvT)
{
  const int s = blockIdx.x, h = blockIdx.y, d = threadIdx.x;
  const long qkOff = ((long)h * S_ + s) * QH_ + d;
  if (d < 64) {
    query[qkOff] = q[(long)s * H_ + h * QH_ + d];
    key[qkOff]   = kv[(long)s * H_ + h * QH_ + d];
    vvT[((long)h * 64 + d) * S_ + s] = kv[(long)s * H_ + h * QH_ + 64 + d];
  } else {
    const int i = d - 64;
    const float p = (float)pos[s];
    const float invf = powf(10000.f, -(float)(2 * (i & 31)) / 64.f);
    const float ang = p * invf;
    const float cc = cosf(ang), sn = sinf(ang);
    const float xq  = (float)q[(long)s * H_ + h * QH_ + 64 + i];
    const float xqr = (i < 32) ? -(float)q[(long)s * H_ + h * QH_ + 64 + i + 32]
                               :  (float)q[(long)s * H_ + h * QH_ + 64 + i - 32];
    query[qkOff] = (bf16)(xq * cc + xqr * sn);
    const float xk  = ckv[(long)s * 320 + 256 + i];
    const float xkr = (i < 32) ? -ckv[(long)s * 320 + 256 + i + 32]
                               :  ckv[(long)s * 320 + 256 + i - 32];
    key[qkOff] = (bf16)(xk * cc + xkr * sn);
  }
}

// ---------------------------------------------------------------------------
// Causal softmax, in place. Reads only cols <= row; writes cols < lim where
// lim = ceil((row+1)/64)*64 (PV's K-causal never reads beyond lim).
// ---------------------------------------------------------------------------
__global__ void __launch_bounds__(256) softmax_causal_k(bf16* __restrict__ sc, long zStride, float scale)
{
  const int row = blockIdx.x, tid = threadIdx.x;
  bf16* p = sc + (long)blockIdx.y * zStride + (long)row * S_;
  float vals[8];
  float mx = -1e30f;
#pragma unroll
  for (int i = 0; i < 8; i++) {
    int c = i * 256 + tid;
    float v = (c <= row) ? (float)p[c] * scale : -1e30f;
    vals[i] = v; mx = fmaxf(mx, v);
  }
#pragma unroll
  for (int o = 32; o; o >>= 1) mx = fmaxf(mx, __shfl_xor(mx, o, 64));
  __shared__ float redA[4], redB[4];
  if ((tid & 63) == 0) redA[tid >> 6] = mx;
  __syncthreads();
  mx = fmaxf(fmaxf(redA[0], redA[1]), fmaxf(redA[2], redA[3]));
  float sum = 0.f;
#pragma unroll
  for (int i = 0; i < 8; i++) { float e = __expf(vals[i] - mx); vals[i] = e; sum += e; }
#pragma unroll
  for (int o = 32; o; o >>= 1) sum += __shfl_xor(sum, o, 64);
  if ((tid & 63) == 0) redB[tid >> 6] = sum;
  __syncthreads();
  sum = redB[0] + redB[1] + redB[2] + redB[3];
  const float rinv = 1.f / sum;
  const int lim = ((row >> 6) + 1) << 6;
#pragma unroll
  for (int i = 0; i < 8; i++) {
    int c = i * 256 + tid;
    if (c < lim) p[c] = (bf16)((c <= row) ? vals[i] * rinv : 0.f);
  }
}

// ---------------------------------------------------------------------------
__global__ void __launch_bounds__(256) gate_k(const bf16* __restrict__ mlp,
                                              const float* __restrict__ gw,
                                              float* __restrict__ probs)
{
  const int s = blockIdx.x, tid = threadIdx.x;
  float acc[8];
#pragma unroll
  for (int e = 0; e < 8; e++) acc[e] = 0.f;
  for (int c = tid; c < H_; c += 256) {
    float x = (float)mlp[(long)s * H_ + c];
#pragma unroll
    for (int e = 0; e < 8; e++) acc[e] += x * gw[e * H_ + c];
  }
  __shared__ float red[4][8];
#pragma unroll
  for (int e = 0; e < 8; e++) {
    float v = acc[e];
#pragma unroll
    for (int o = 32; o; o >>= 1) v += __shfl_xor(v, o, 64);
    if ((tid & 63) == 0) red[tid >> 6][e] = v;
  }
  __syncthreads();
  if (tid == 0) {
    float l[8]; float mx = -1e30f;
#pragma unroll
    for (int e = 0; e < 8; e++) { l[e] = red[0][e] + red[1][e] + red[2][e] + red[3][e]; mx = fmaxf(mx, l[e]); }
    float sum = 0.f;
#pragma unroll
    for (int e = 0; e < 8; e++) { l[e] = __expf(l[e] - mx); sum += l[e]; }
    float r = 1.f / sum;
#pragma unroll
    for (int e = 0; e < 8; e++) probs[(long)s * 8 + e] = l[e] * r;
  }
}

// ---------------------------------------------------------------------------
__global__ void __launch_bounds__(256) wconv_k(const float* __restrict__ in,
                                               bf16* __restrict__ out, int n8)
{
  int i = blockIdx.x * 256 + threadIdx.x;
  if (i < n8) {
    f32x4 a = ((const f32x4*)in)[2 * i];
    f32x4 b = ((const f32x4*)in)[2 * i + 1];
    bf16x8 v;
    v[0] = (bf16)a[0]; v[1] = (bf16)a[1]; v[2] = (bf16)a[2]; v[3] = (bf16)a[3];
    v[4] = (bf16)b[0]; v[5] = (bf16)b[1]; v[6] = (bf16)b[2]; v[7] = (bf16)b[3];
    ((bf16x8*)out)[i] = v;
  }
}

// ---------------------------------------------------------------------------
extern "C" void kernel_launch(void* const* d_in, const int* in_sizes, int n_in,
                              void* d_out, int out_size, void* d_ws, size_t ws_size,
                              hipStream_t stream)
{
  const int*   positions = (const int*)  d_in[0];
  const float* hidden    = (const float*)d_in[1];
  const float* ln1       = (const float*)d_in[2];
  const float* wq        = (const float*)d_in[3];
  const float* wkva      = (const float*)d_in[4];
  const float* lnkv      = (const float*)d_in[5];
  const float* wkvb      = (const float*)d_in[6];
  const float* wo        = (const float*)d_in[7];
  const float* ln2       = (const float*)d_in[8];
  const float* wg        = (const float*)d_in[9];
  const float* wfc1      = (const float*)d_in[10];
  const float* wfc2      = (const float*)d_in[11];
  float* out = (float*)d_out;

  char* wsb = (char*)d_ws;
  size_t off = 0;
  auto alloc = [&](size_t bytes) -> void* {
    void* p = wsb + off;
    off += (bytes + 255) & ~(size_t)255;
    return p;
  };
  bf16*  sa_in = (bf16*) alloc((size_t)S_ * H_ * 2);
  bf16*  qb    = (bf16*) alloc((size_t)S_ * H_ * 2);
  float* ckv   = (float*)alloc((size_t)S_ * 320 * 4);
  bf16*  ckvn  = (bf16*) alloc((size_t)S_ * KV_RANK_ * 2);
  bf16*  kvb   = (bf16*) alloc((size_t)S_ * H_ * 2);
  bf16*  query = (bf16*) alloc((size_t)NH_ * S_ * QH_ * 2);
  bf16*  key   = (bf16*) alloc((size_t)NH_ * S_ * QH_ * 2);
  bf16*  vvT   = (bf16*) alloc((size_t)NH_ * 64 * S_ * 2);
  bf16*  ctx   = (bf16*) alloc((size_t)S_ * NH_ * 64 * 2);
  bf16*  mlp   = (bf16*) alloc((size_t)S_ * H_ * 2);
  float* probs = (float*)alloc((size_t)S_ * 8 * 4);
  bf16*  hbuf  = (bf16*) alloc((size_t)S_ * EXP_ * INTER_ * 2);

  const size_t MBy = (size_t)1 << 20;
  const size_t rem = (ws_size > off) ? ws_size - off : 0;
  const size_t szSS   = (size_t)S_ * S_ * 2;                 // 8.39 MB / head
  const size_t szMoeW = (size_t)EXP_ * INTER_ * H_ * 2;      // 46.1 MB each

  int tier;
  if      (rem >= 136 * MBy) tier = 1;   // scores x16; MoE bf16 aliased
  else if (rem >=  94 * MBy) tier = 2;   // scores x4;  MoE bf16 aliased
  else                       tier = 3;   // scores x1;  fp32 weights direct
  const bool cw = (tier <= 2);
  const int nz = (tier == 1) ? 16 : (tier == 2 ? 4 : 1);

  char* R = (char*)alloc(tier == 1 ? 16 * szSS : (tier == 2 ? 2 * szMoeW : szSS));
  bf16* scores = (bf16*)R;
  bf16* fc1b   = (bf16*)R;                 // valid after attention (tier<=2)
  bf16* fc2b   = (bf16*)(R + szMoeW);
  // attention weights (bf16) alias hbuf (dead until fc1)
  bf16* wqb   = (bf16*)hbuf;
  bf16* wkvab = wqb   + (size_t)H_ * H_;
  bf16* wkvbb = wkvab + (size_t)320 * H_;
  bf16* wob   = wkvbb + (size_t)H_ * KV_RANK_;

  const float scale = 0.08838834764831845f;   // 128^-0.5
  const long zQ = (long)S_ * QH_, zS = (long)S_ * S_, zV = (long)64 * S_;

  rmsnorm_k<8><<<S_, 256, 0, stream>>>(hidden, ln1, sa_in, H_);

  if (cw) {
    wconv_k<<<(H_*H_/8 + 255)/256, 256, 0, stream>>>(wq, wqb, H_*H_/8);
    wconv_k<<<(320*H_/8 + 255)/256, 256, 0, stream>>>(wkva, wkvab, 320*H_/8);
    wconv_k<<<(H_*KV_RANK_/8 + 255)/256, 256, 0, stream>>>(wkvb, wkvbb, H_*KV_RANK_/8);
    wconv_k<<<(H_*NH_*64/8 + 255)/256, 256, 0, stream>>>(wo, wob, H_*NH_*64/8);
  }

  // q_proj [2048x2048, K=2048]
  if (cw) gemm_bt<EPI_BF16, bf16, 64><<<dim3(32,32,1), 256, 0, stream>>>(
      sa_in, wqb, qb, hidden, S_, H_, H_, H_, H_, H_, 0, 0,0,0,0,0, 0,0,0);
  else    gemm_bt<EPI_BF16, float, 64><<<dim3(32,32,1), 256, 0, stream>>>(
      sa_in, wq,  qb, hidden, S_, H_, H_, H_, H_, H_, 0, 0,0,0,0,0, 0,0,0);

  // kv_a [2048x320, K=2048] -> fp32
  if (cw) gemm_bt<EPI_F32, bf16, 64><<<dim3(5,32,1), 256, 0, stream>>>(
      sa_in, wkvab, ckv, hidden, S_, 320, H_, H_, H_, 320, 0, 0,0,0,0,0, 0,0,0);
  else    gemm_bt<EPI_F32, float, 64><<<dim3(5,32,1), 256, 0, stream>>>(
      sa_in, wkva,  ckv, hidden, S_, 320, H_, H_, H_, 320, 0, 0,0,0,0,0, 0,0,0);

  rmsnorm_k<1><<<S_, 256, 0, stream>>>(ckv, lnkv, ckvn, 320);

  // kv_b [2048x2048, K=256]
  if (cw) gemm_bt<EPI_BF16, bf16, 64><<<dim3(32,32,1), 256, 0, stream>>>(
      ckvn, wkvbb, kvb, hidden, S_, H_, KV_RANK_, KV_RANK_, KV_RANK_, H_, 0, 0,0,0,0,0, 0,0,0);
  else    gemm_bt<EPI_BF16, float, 64><<<dim3(32,32,1), 256, 0, stream>>>(
      ckvn, wkvb,  kvb, hidden, S_, H_, KV_RANK_, KV_RANK_, KV_RANK_, H_, 0, 0,0,0,0,0, 0,0,0);

  prep_qkv_k<<<dim3(S_, NH_), 128, 0, stream>>>(qb, kvb, ckv, positions, query, key, vvT);

  for (int l = 0; l < NH_ / nz; l++) {
    gemm_bt<EPI_BF16, bf16, 128><<<dim3(16,16,nz), 256, 0, stream>>>(
        query + (long)l*nz*zQ, key + (long)l*nz*zQ, scores, hidden,
        S_, S_, QH_, QH_, QH_, S_, 1, zQ, zQ, zS, 0,0, 0,0,0);
    softmax_causal_k<<<dim3(S_, nz), 256, 0, stream>>>(scores, zS, scale);
    gemm_bt<EPI_BF16, bf16, 64><<<dim3(1,32,nz), 256, 0, stream>>>(
        scores, vvT + (long)l*nz*zV, ctx + (long)l*nz*64, hidden,
        S_, 64, S_, S_, S_, NH_*64, 2, zS, zV, 64, 0,0, 0,0,0);
  }

  // MoE bf16 conversion (scores region dead now)
  if (cw) {
    wconv_k<<<(EXP_*INTER_*H_/8 + 255)/256, 256, 0, stream>>>(wfc1, fc1b, EXP_*INTER_*H_/8);
    wconv_k<<<(EXP_*INTER_*H_/8 + 255)/256, 256, 0, stream>>>(wfc2, fc2b, EXP_*INTER_*H_/8);
  }

  // o_proj: out = hidden + ctx @ wo^T   (writes d_out directly)
  if (cw) gemm_bt<EPI_ADD, bf16, 64><<<dim3(32,32,1), 256, 0, stream>>>(
      ctx, wob, out, hidden, S_, H_, NH_*64, NH_*64, NH_*64, H_, 0, 0,0,0,0, H_, 0,0,0);
  else    gemm_bt<EPI_ADD, float, 64><<<dim3(32,32,1), 256, 0, stream>>>(
      ctx, wo,  out, hidden, S_, H_, NH_*64, NH_*64, NH_*64, H_, 0, 0,0,0,0, H_, 0,0,0);

  rmsnorm_k<8><<<S_, 256, 0, stream>>>(out, ln2, mlp, H_);
  gate_k<<<S_, 256, 0, stream>>>(mlp, wg, probs);

  // fc1: hbuf[s][e*1408+i] = silu(mlp @ fc1_w[e]^T) * probs[s][e]
  if (cw) gemm_bt<EPI_SILU, bf16, 128><<<dim3(11,16,8), 256, 0, stream>>>(
      mlp, fc1b, hbuf, probs, S_, INTER_, H_, H_, H_, EXP_*INTER_, 0,
      0, (long)INTER_*H_, INTER_, 1, 8, 0, 0, 0);
  else    gemm_bt<EPI_SILU, float, 128><<<dim3(11,16,8), 256, 0, stream>>>(
      mlp, wfc1, hbuf, probs, S_, INTER_, H_, H_, H_, EXP_*INTER_, 0,
      0, (long)INTER_*H_, INTER_, 1, 8, 0, 0, 0);

  // fc2: split-K z=4 (2 experts each), atomicAdd fp32 into out
  if (cw) gemm_bt<EPI_ATOM, bf16, 128><<<dim3(16,16,4), 256, 0, stream>>>(
      hbuf, fc2b, out, hidden, S_, H_, 2*INTER_, EXP_*INTER_, 0, H_, 0,
      (long)2*INTER_, 0, 0, 0, 0, INTER_, (long)H_*INTER_, 2);
  else    gemm_bt<EPI_ATOM, float, 128><<<dim3(16,16,4), 256, 0, stream>>>(
      hbuf, wfc2, out, hidden, S_, H_, 2*INTER_, EXP_*INTER_, 0, H_, 0,
      (long)2*INTER_, 0, 0, 0, 0, INTER_, (long)H_*INTER_, 2);
}

// Round 4
// 748.124 us; speedup vs baseline: 2.2582x; 1.0568x over previous
//
#include <hip/hip_runtime.h>
#include <cstdint>
#include <cstddef>

typedef __bf16 bf16;
typedef __bf16 bf16x8 __attribute__((ext_vector_type(8)));
typedef float  f32x4  __attribute__((ext_vector_type(4)));

constexpr int S_      = 2048;
constexpr int H_      = 2048;
constexpr int NH_     = 16;
constexpr int KV_RANK_= 256;
constexpr int EXP_    = 8;
constexpr int INTER_  = 1408;
constexpr int QH_     = 128;
constexpr float EPS_  = 1e-6f;

__device__ inline void gload16(const void* g, void* l) {
  __builtin_amdgcn_global_load_lds(
      (const __attribute__((address_space(1))) void*)g,
      (__attribute__((address_space(3))) void*)l, 16, 0, 0);
}

enum { EPI_BF16 = 0, EPI_F32 = 1, EPI_ADD = 2, EPI_SILU = 3, EPI_ATOM = 4 };

// ---------------------------------------------------------------------------
// MFMA GEMM: C[M,N] (+)= A[M,K] @ B[N,K]^T   (BK=64, TILE in {64,128})
//  4 waves as 2x2, each wave (TILE/2)^2 via FRxFRx2 mfma_f32_16x16x32_bf16.
//  XOR-swizzled LDS (conflict-free), staging via global_load_lds width=16.
//  kPerE>0: flat-K MoE, B base hops every kPerE cols by bExpStride.
// ---------------------------------------------------------------------------
template <int EPI, typename TB, int TILE>
__global__ void __launch_bounds__(256, 3) gemm_bt(
    const bf16* __restrict__ A, const TB* __restrict__ B,
    void* __restrict__ Cv, const float* __restrict__ aux,
    int M, int N, int K, int lda, int ldb, int ldc,
    long zA, long zB, long zC, long auxZ, int auxRS,
    int kPerE, long bExpStride, int expBasePerZ)
{
  constexpr int FR = TILE / 32;
  const int tileN = blockIdx.x * TILE;
  const int tileM = blockIdx.y * TILE;
  const int z = blockIdx.z;
  A += (long)z * zA;

  __shared__ __align__(16) bf16 As[TILE * 64];
  __shared__ __align__(16) TB   Bs[TILE * 64];
  char* AsB = (char*)As;
  char* BsB = (char*)Bs;

  const int tid  = threadIdx.x;
  const int lane = tid & 63;
  const int wave = tid >> 6;
  const int wr = wave >> 1, wc = wave & 1;
  const int quad = lane >> 4, r16 = lane & 15;

  const int ldbe = (kPerE > 0) ? kPerE : ldb;
  const TB* BzBase = (kPerE > 0) ? (B + (long)z * expBasePerZ * bExpStride)
                                 : (B + (long)z * zB);

  constexpr int IA = TILE / 32;
  const bf16* aG[IA]; char* aL[IA];
#pragma unroll
  for (int i = 0; i < IA; i++) {
    int n = (wave * IA + i) * 64 + lane;
    int row = n >> 3, cp = n & 7;
    int cc = (cp ^ (row & 7)) << 3;
    int rowg = tileM + row; if (rowg > M - 1) rowg = M - 1;
    aG[i] = A + (long)rowg * lda + cc;
    aL[i] = AsB + (long)(wave * IA + i) * 1024;
  }
  constexpr int IB = (sizeof(TB) == 4) ? (TILE / 16) : (TILE / 32);
  const TB* bG[IB]; char* bL[IB];
#pragma unroll
  for (int i = 0; i < IB; i++) {
    int n = (wave * IB + i) * 64 + lane;
    int row, cc;
    if constexpr (sizeof(TB) == 4) { row = n >> 4; cc = ((n & 15) ^ (row & 15)) << 2; }
    else                           { row = n >> 3; cc = ((n & 7)  ^ (row & 7))  << 3; }
    int rowg = tileN + row; if (rowg > N - 1) rowg = N - 1;
    bG[i] = BzBase + (long)rowg * ldbe + cc;
    bL[i] = BsB + (long)(wave * IB + i) * 1024;
  }

  int aOff[FR], bOff[FR];
#pragma unroll
  for (int i = 0; i < FR; i++) {
    int row = wr * (TILE / 2) + i * 16 + r16;
    aOff[i] = row * 128 + ((quad ^ (row & 7)) << 4);
  }
#pragma unroll
  for (int j = 0; j < FR; j++) {
    int row = wc * (TILE / 2) + j * 16 + r16;
    if constexpr (sizeof(TB) == 4) bOff[j] = row * 256 + (((2 * quad) ^ (row & 15)) << 4);
    else                           bOff[j] = row * 128 + ((quad ^ (row & 7)) << 4);
  }

  f32x4 acc[FR][FR];
#pragma unroll
  for (int i = 0; i < FR; i++)
#pragma unroll
    for (int j = 0; j < FR; j++)
#pragma unroll
      for (int r = 0; r < 4; r++) acc[i][j][r] = 0.f;

  int bk = 0; long eOff = 0;
  for (int k0 = 0; k0 < K; k0 += 64) {
#pragma unroll
    for (int i = 0; i < IA; i++) gload16(aG[i] + k0, aL[i]);
#pragma unroll
    for (int i = 0; i < IB; i++) gload16(bG[i] + eOff + bk, bL[i]);
    __syncthreads();

#pragma unroll
    for (int s = 0; s < 2; s++) {
      bf16x8 af[FR], bfv[FR];
#pragma unroll
      for (int i = 0; i < FR; i++)
        af[i] = *(const bf16x8*)(AsB + (aOff[i] ^ (s << 6)));
#pragma unroll
      for (int j = 0; j < FR; j++) {
        if constexpr (sizeof(TB) == 2) {
          bfv[j] = *(const bf16x8*)(BsB + (bOff[j] ^ (s << 6)));
        } else {
          int a0 = bOff[j] ^ (s << 7);
          f32x4 lo = *(const f32x4*)(BsB + a0);
          f32x4 hi = *(const f32x4*)(BsB + (a0 ^ 16));
          bf16x8 v;
          v[0]=(bf16)lo[0]; v[1]=(bf16)lo[1]; v[2]=(bf16)lo[2]; v[3]=(bf16)lo[3];
          v[4]=(bf16)hi[0]; v[5]=(bf16)hi[1]; v[6]=(bf16)hi[2]; v[7]=(bf16)hi[3];
          bfv[j] = v;
        }
      }
#pragma unroll
      for (int i = 0; i < FR; i++)
#pragma unroll
        for (int j = 0; j < FR; j++)
          acc[i][j] = __builtin_amdgcn_mfma_f32_16x16x32_bf16(af[i], bfv[j], acc[i][j], 0, 0, 0);
    }
    __syncthreads();

    bk += 64;
    if (kPerE > 0 && bk >= kPerE) { bk = 0; eOff += bExpStride; }
  }

  bf16*  Cb = (bf16*)Cv + (long)z * zC;
  float* Cf = (float*)Cv + (long)z * zC;
  const float* auxp = aux + (long)z * auxZ;
  const int mB = tileM + wr * (TILE / 2) + quad * 4;
  const int nB = tileN + wc * (TILE / 2) + r16;
#pragma unroll
  for (int i = 0; i < FR; i++) {
#pragma unroll
    for (int r = 0; r < 4; r++) {
      int gm = mB + i * 16 + r;
      if (gm >= M) continue;
      float rowAux = 0.f;
      if constexpr (EPI == EPI_SILU) rowAux = auxp[(long)gm * auxRS];
#pragma unroll
      for (int j = 0; j < FR; j++) {
        int gn = nB + j * 16;
        if (gn >= N) continue;
        float v = acc[i][j][r];
        long off = (long)gm * ldc + gn;
        if constexpr (EPI == EPI_BF16)      Cb[off] = (bf16)v;
        else if constexpr (EPI == EPI_F32)  Cf[off] = v;
        else if constexpr (EPI == EPI_ADD)  Cf[off] = auxp[(long)gm * auxRS + gn] + v;
        else if constexpr (EPI == EPI_SILU) { float sv = v / (1.f + __expf(-v)); Cb[off] = (bf16)(sv * rowAux); }
        else                                atomicAdd(&Cf[off], v);
      }
    }
  }
}

// ---------------------------------------------------------------------------
// Flash attention (causal): Q,K [NH][S][128], V^T [NH][64][S] -> ctx [S][NH*64]
// grid (NH, S/64); 4 waves, wave w owns q-rows qt*64+w*16..+15.
// Per 64-key tile: K/V staged via swizzled global_load_lds; QK^T MFMA;
// per-wave online softmax (rows wave-private); P C->A layout via per-wave
// swizzled LDS (no barrier); PV MFMA into fp32 regs.
// ---------------------------------------------------------------------------
__global__ void __launch_bounds__(256) flash_k(
    const bf16* __restrict__ q, const bf16* __restrict__ k,
    const bf16* __restrict__ vt, bf16* __restrict__ ctx, float scale)
{
  const int h  = blockIdx.x;
  const int qt = (int)gridDim.y - 1 - (int)blockIdx.y;   // long blocks first
  const int tid = threadIdx.x, lane = tid & 63, wave = tid >> 6;
  const int quad = lane >> 4, r16 = lane & 15;

  __shared__ __align__(16) bf16 Ks[64 * 128];   // [key][d]  16-chunk swizzle
  __shared__ __align__(16) bf16 Vs[64 * 64];    // [d][key]   8-chunk swizzle
  __shared__ __align__(16) bf16 Ps[4][16 * 64]; // per-wave P, 8-chunk swizzle
  char* KsB = (char*)Ks;
  char* VsB = (char*)Vs;
  char* PsB = (char*)&Ps[wave][0];

  // Q fragments in registers: A[m=r16][k=quad*8+j], k-subtile ks
  bf16x8 qf[4];
  {
    const bf16* qp = q + ((long)h * S_ + qt * 64 + wave * 16 + r16) * 128 + quad * 8;
#pragma unroll
    for (int ks = 0; ks < 4; ks++) qf[ks] = *(const bf16x8*)(qp + ks * 32);
  }

  // staging addresses (k-tile-invariant)
  const bf16* kG[4]; char* kL[4];
#pragma unroll
  for (int i = 0; i < 4; i++) {
    int n = (wave * 4 + i) * 64 + lane;
    int row = n >> 4, c = n & 15;
    kG[i] = k + ((long)h * S_ + row) * 128 + ((c ^ (row & 15)) << 3);
    kL[i] = KsB + (long)(wave * 4 + i) * 1024;
  }
  const bf16* vG[2]; char* vL[2];
#pragma unroll
  for (int i = 0; i < 2; i++) {
    int n = (wave * 2 + i) * 64 + lane;
    int row = n >> 3, c = n & 7;
    vG[i] = vt + ((long)h * 64 + row) * S_ + ((c ^ (row & 7)) << 3);
    vL[i] = VsB + (long)(wave * 2 + i) * 1024;
  }

  float mr[4], lr[4];
#pragma unroll
  for (int r = 0; r < 4; r++) { mr[r] = -1e30f; lr[r] = 0.f; }
  f32x4 o[4];
#pragma unroll
  for (int j = 0; j < 4; j++)
#pragma unroll
    for (int r = 0; r < 4; r++) o[j][r] = 0.f;

  for (int kt = 0; kt <= qt; kt++) {
#pragma unroll
    for (int i = 0; i < 4; i++) gload16(kG[i] + (long)kt * 64 * 128, kL[i]);
#pragma unroll
    for (int i = 0; i < 2; i++) gload16(vG[i] + kt * 64, vL[i]);
    __syncthreads();

    // S = Q K^T for this tile: frag j = keys j*16..+15
    f32x4 s[4];
#pragma unroll
    for (int j = 0; j < 4; j++)
#pragma unroll
      for (int r = 0; r < 4; r++) s[j][r] = 0.f;
#pragma unroll
    for (int ks = 0; ks < 4; ks++) {
#pragma unroll
      for (int j = 0; j < 4; j++) {
        int row = j * 16 + r16;
        int c = ks * 4 + quad;
        bf16x8 bfr = *(const bf16x8*)(KsB + row * 256 + ((c ^ (row & 15)) << 4));
        s[j] = __builtin_amdgcn_mfma_f32_16x16x32_bf16(qf[ks], bfr, s[j], 0, 0, 0);
      }
    }

    if (kt == qt) {   // diagonal tile: mask key > qrow
#pragma unroll
      for (int j = 0; j < 4; j++)
#pragma unroll
        for (int r = 0; r < 4; r++)
          if (j * 16 + r16 > wave * 16 + quad * 4 + r) s[j][r] = -1e30f;
    }

    // online softmax; row r lives on 16 lanes (r16 group), cols = r16+16j
    float pj[4][4];
#pragma unroll
    for (int r = 0; r < 4; r++) {
      float mx = fmaxf(fmaxf(s[0][r], s[1][r]), fmaxf(s[2][r], s[3][r]));
#pragma unroll
      for (int off = 1; off < 16; off <<= 1) mx = fmaxf(mx, __shfl_xor(mx, off, 64));
      mx *= scale;
      float nm = fmaxf(mr[r], mx);
      float alpha = __expf(mr[r] - nm);
      mr[r] = nm;
      float rs = 0.f;
#pragma unroll
      for (int j = 0; j < 4; j++) { float e = __expf(s[j][r] * scale - nm); pj[j][r] = e; rs += e; }
#pragma unroll
      for (int off = 1; off < 16; off <<= 1) rs += __shfl_xor(rs, off, 64);
      lr[r] = lr[r] * alpha + rs;
#pragma unroll
      for (int j = 0; j < 4; j++) o[j][r] *= alpha;
    }

    // P -> per-wave LDS in A-readable swizzled layout
#pragma unroll
    for (int j = 0; j < 4; j++) {
      int chunk = j * 2 + (r16 >> 3);
#pragma unroll
      for (int r = 0; r < 4; r++) {
        int row = quad * 4 + r;
        *(bf16*)(PsB + row * 128 + ((chunk ^ (row & 7)) << 4) + ((r16 & 7) << 1)) = (bf16)pj[j][r];
      }
    }

    // o += P V : A = P (m=r16, k over 64 keys), B = V^T (n=d frag j)
#pragma unroll
    for (int ks = 0; ks < 2; ks++) {
      int c = ks * 4 + quad;
      bf16x8 af = *(const bf16x8*)(PsB + r16 * 128 + ((c ^ (r16 & 7)) << 4));
#pragma unroll
      for (int j = 0; j < 4; j++) {
        int row = j * 16 + r16;
        bf16x8 bfr = *(const bf16x8*)(VsB + row * 128 + ((c ^ (row & 7)) << 4));
        o[j] = __builtin_amdgcn_mfma_f32_16x16x32_bf16(af, bfr, o[j], 0, 0, 0);
      }
    }
    __syncthreads();
  }

  // epilogue: ctx[qrow][h*64 + d] = o / l
  bf16* cp = ctx + ((long)(qt * 64 + wave * 16 + quad * 4)) * (NH_ * 64) + h * 64 + r16;
#pragma unroll
  for (int r = 0; r < 4; r++) {
    float rl = 1.f / lr[r];
#pragma unroll
    for (int j = 0; j < 4; j++)
      cp[(long)r * NH_ * 64 + j * 16] = (bf16)(o[j][r] * rl);
  }
}

// ---------------------------------------------------------------------------
template <int NIT>
__global__ void __launch_bounds__(256) rmsnorm_k(
    const float* __restrict__ x, const float* __restrict__ w,
    bf16* __restrict__ out, int inStride)
{
  const int row = blockIdx.x, tid = threadIdx.x;
  const float* xr = x + (long)row * inStride;
  float vals[NIT];
  float ss = 0.f;
#pragma unroll
  for (int i = 0; i < NIT; i++) { float v = xr[i * 256 + tid]; vals[i] = v; ss += v * v; }
#pragma unroll
  for (int o = 32; o; o >>= 1) ss += __shfl_xor(ss, o, 64);
  __shared__ float red[4];
  if ((tid & 63) == 0) red[tid >> 6] = ss;
  __syncthreads();
  ss = red[0] + red[1] + red[2] + red[3];
  const float rinv = rsqrtf(ss / (float)(NIT * 256) + EPS_);
  bf16* orow = out + (long)row * (NIT * 256);
#pragma unroll
  for (int i = 0; i < NIT; i++) { int c = i * 256 + tid; orow[c] = (bf16)(w[c] * vals[i] * rinv); }
}

// ---------------------------------------------------------------------------
__global__ void prep_qkv_k(const bf16* __restrict__ q, const bf16* __restrict__ kv,
                           const float* __restrict__ ckv, const int* __restrict__ pos,
                           bf16* __restrict__ query, bf16* __restrict__ key,
                           bf16* __restrict__ vvT)
{
  const int s = blockIdx.x, h = blockIdx.y, d = threadIdx.x;
  const long qkOff = ((long)h * S_ + s) * QH_ + d;
  if (d < 64) {
    query[qkOff] = q[(long)s * H_ + h * QH_ + d];
    key[qkOff]   = kv[(long)s * H_ + h * QH_ + d];
    vvT[((long)h * 64 + d) * S_ + s] = kv[(long)s * H_ + h * QH_ + 64 + d];
  } else {
    const int i = d - 64;
    const float p = (float)pos[s];
    const float invf = powf(10000.f, -(float)(2 * (i & 31)) / 64.f);
    const float ang = p * invf;
    const float cc = cosf(ang), sn = sinf(ang);
    const float xq  = (float)q[(long)s * H_ + h * QH_ + 64 + i];
    const float xqr = (i < 32) ? -(float)q[(long)s * H_ + h * QH_ + 64 + i + 32]
                               :  (float)q[(long)s * H_ + h * QH_ + 64 + i - 32];
    query[qkOff] = (bf16)(xq * cc + xqr * sn);
    const float xk  = ckv[(long)s * 320 + 256 + i];
    const float xkr = (i < 32) ? -ckv[(long)s * 320 + 256 + i + 32]
                               :  ckv[(long)s * 320 + 256 + i - 32];
    key[qkOff] = (bf16)(xk * cc + xkr * sn);
  }
}

// ---------------------------------------------------------------------------
__global__ void __launch_bounds__(256) gate_k(const bf16* __restrict__ mlp,
                                              const float* __restrict__ gw,
                                              float* __restrict__ probs)
{
  const int s = blockIdx.x, tid = threadIdx.x;
  float acc[8];
#pragma unroll
  for (int e = 0; e < 8; e++) acc[e] = 0.f;
  for (int c = tid; c < H_; c += 256) {
    float x = (float)mlp[(long)s * H_ + c];
#pragma unroll
    for (int e = 0; e < 8; e++) acc[e] += x * gw[e * H_ + c];
  }
  __shared__ float red[4][8];
#pragma unroll
  for (int e = 0; e < 8; e++) {
    float v = acc[e];
#pragma unroll
    for (int o = 32; o; o >>= 1) v += __shfl_xor(v, o, 64);
    if ((tid & 63) == 0) red[tid >> 6][e] = v;
  }
  __syncthreads();
  if (tid == 0) {
    float l[8]; float mx = -1e30f;
#pragma unroll
    for (int e = 0; e < 8; e++) { l[e] = red[0][e] + red[1][e] + red[2][e] + red[3][e]; mx = fmaxf(mx, l[e]); }
    float sum = 0.f;
#pragma unroll
    for (int e = 0; e < 8; e++) { l[e] = __expf(l[e] - mx); sum += l[e]; }
    float r = 1.f / sum;
#pragma unroll
    for (int e = 0; e < 8; e++) probs[(long)s * 8 + e] = l[e] * r;
  }
}

// ---------------------------------------------------------------------------
__global__ void __launch_bounds__(256) wconv_k(const float* __restrict__ in,
                                               bf16* __restrict__ out, int n8)
{
  int i = blockIdx.x * 256 + threadIdx.x;
  if (i < n8) {
    f32x4 a = ((const f32x4*)in)[2 * i];
    f32x4 b = ((const f32x4*)in)[2 * i + 1];
    bf16x8 v;
    v[0] = (bf16)a[0]; v[1] = (bf16)a[1]; v[2] = (bf16)a[2]; v[3] = (bf16)a[3];
    v[4] = (bf16)b[0]; v[5] = (bf16)b[1]; v[6] = (bf16)b[2]; v[7] = (bf16)b[3];
    ((bf16x8*)out)[i] = v;
  }
}

// ---------------------------------------------------------------------------
extern "C" void kernel_launch(void* const* d_in, const int* in_sizes, int n_in,
                              void* d_out, int out_size, void* d_ws, size_t ws_size,
                              hipStream_t stream)
{
  const int*   positions = (const int*)  d_in[0];
  const float* hidden    = (const float*)d_in[1];
  const float* ln1       = (const float*)d_in[2];
  const float* wq        = (const float*)d_in[3];
  const float* wkva      = (const float*)d_in[4];
  const float* lnkv      = (const float*)d_in[5];
  const float* wkvb      = (const float*)d_in[6];
  const float* wo        = (const float*)d_in[7];
  const float* ln2       = (const float*)d_in[8];
  const float* wg        = (const float*)d_in[9];
  const float* wfc1      = (const float*)d_in[10];
  const float* wfc2      = (const float*)d_in[11];
  float* out = (float*)d_out;

  char* wsb = (char*)d_ws;
  size_t off = 0;
  auto alloc = [&](size_t bytes) -> void* {
    void* p = wsb + off;
    off += (bytes + 255) & ~(size_t)255;
    return p;
  };
  bf16*  sa_in = (bf16*) alloc((size_t)S_ * H_ * 2);
  bf16*  qb    = (bf16*) alloc((size_t)S_ * H_ * 2);
  float* ckv   = (float*)alloc((size_t)S_ * 320 * 4);
  bf16*  ckvn  = (bf16*) alloc((size_t)S_ * KV_RANK_ * 2);
  bf16*  kvb   = (bf16*) alloc((size_t)S_ * H_ * 2);
  bf16*  query = (bf16*) alloc((size_t)NH_ * S_ * QH_ * 2);
  bf16*  key   = (bf16*) alloc((size_t)NH_ * S_ * QH_ * 2);
  bf16*  vvT   = (bf16*) alloc((size_t)NH_ * 64 * S_ * 2);
  bf16*  ctx   = (bf16*) alloc((size_t)S_ * NH_ * 64 * 2);
  bf16*  mlp   = (bf16*) alloc((size_t)S_ * H_ * 2);
  float* probs = (float*)alloc((size_t)S_ * 8 * 4);
  bf16*  hbuf  = (bf16*) alloc((size_t)S_ * EXP_ * INTER_ * 2);

  const size_t MBy = (size_t)1 << 20;
  const size_t rem = (ws_size > off) ? ws_size - off : 0;
  const size_t szMoeW = (size_t)EXP_ * INTER_ * H_ * 2;      // 46.1 MB each
  const bool cw = (rem >= 93 * MBy);

  bf16* fc1b = nullptr; bf16* fc2b = nullptr;
  if (cw) { fc1b = (bf16*)alloc(szMoeW); fc2b = (bf16*)alloc(szMoeW); }
  // attention weights (bf16) alias hbuf (dead until fc1; o_proj finishes first)
  bf16* wqb   = (bf16*)hbuf;
  bf16* wkvab = wqb   + (size_t)H_ * H_;
  bf16* wkvbb = wkvab + (size_t)320 * H_;
  bf16* wob   = wkvbb + (size_t)H_ * KV_RANK_;

  const float scale = 0.08838834764831845f;   // 128^-0.5

  rmsnorm_k<8><<<S_, 256, 0, stream>>>(hidden, ln1, sa_in, H_);

  if (cw) {
    wconv_k<<<(H_*H_/8 + 255)/256, 256, 0, stream>>>(wq, wqb, H_*H_/8);
    wconv_k<<<(320*H_/8 + 255)/256, 256, 0, stream>>>(wkva, wkvab, 320*H_/8);
    wconv_k<<<(H_*KV_RANK_/8 + 255)/256, 256, 0, stream>>>(wkvb, wkvbb, H_*KV_RANK_/8);
    wconv_k<<<(H_*NH_*64/8 + 255)/256, 256, 0, stream>>>(wo, wob, H_*NH_*64/8);
    wconv_k<<<(EXP_*INTER_*H_/8 + 255)/256, 256, 0, stream>>>(wfc1, fc1b, EXP_*INTER_*H_/8);
    wconv_k<<<(EXP_*INTER_*H_/8 + 255)/256, 256, 0, stream>>>(wfc2, fc2b, EXP_*INTER_*H_/8);
  }

  // q_proj [2048x2048, K=2048]
  if (cw) gemm_bt<EPI_BF16, bf16, 64><<<dim3(32,32,1), 256, 0, stream>>>(
      sa_in, wqb, qb, hidden, S_, H_, H_, H_, H_, H_, 0,0,0,0,0, 0,0,0);
  else    gemm_bt<EPI_BF16, float, 64><<<dim3(32,32,1), 256, 0, stream>>>(
      sa_in, wq,  qb, hidden, S_, H_, H_, H_, H_, H_, 0,0,0,0,0, 0,0,0);

  // kv_a [2048x320, K=2048] -> fp32
  if (cw) gemm_bt<EPI_F32, bf16, 64><<<dim3(5,32,1), 256, 0, stream>>>(
      sa_in, wkvab, ckv, hidden, S_, 320, H_, H_, H_, 320, 0,0,0,0,0, 0,0,0);
  else    gemm_bt<EPI_F32, float, 64><<<dim3(5,32,1), 256, 0, stream>>>(
      sa_in, wkva,  ckv, hidden, S_, 320, H_, H_, H_, 320, 0,0,0,0,0, 0,0,0);

  rmsnorm_k<1><<<S_, 256, 0, stream>>>(ckv, lnkv, ckvn, 320);

  // kv_b [2048x2048, K=256]
  if (cw) gemm_bt<EPI_BF16, bf16, 64><<<dim3(32,32,1), 256, 0, stream>>>(
      ckvn, wkvbb, kvb, hidden, S_, H_, KV_RANK_, KV_RANK_, KV_RANK_, H_, 0,0,0,0,0, 0,0,0);
  else    gemm_bt<EPI_BF16, float, 64><<<dim3(32,32,1), 256, 0, stream>>>(
      ckvn, wkvb,  kvb, hidden, S_, H_, KV_RANK_, KV_RANK_, KV_RANK_, H_, 0,0,0,0,0, 0,0,0);

  prep_qkv_k<<<dim3(S_, NH_), 128, 0, stream>>>(qb, kvb, ckv, positions, query, key, vvT);

  // fused causal attention -> ctx
  flash_k<<<dim3(NH_, S_/64), 256, 0, stream>>>(query, key, vvT, ctx, scale);

  // o_proj: out = hidden + ctx @ wo^T   (writes d_out directly)
  if (cw) gemm_bt<EPI_ADD, bf16, 64><<<dim3(32,32,1), 256, 0, stream>>>(
      ctx, wob, out, hidden, S_, H_, NH_*64, NH_*64, NH_*64, H_, 0,0,0,0, H_, 0,0,0);
  else    gemm_bt<EPI_ADD, float, 64><<<dim3(32,32,1), 256, 0, stream>>>(
      ctx, wo,  out, hidden, S_, H_, NH_*64, NH_*64, NH_*64, H_, 0,0,0,0, H_, 0,0,0);

  rmsnorm_k<8><<<S_, 256, 0, stream>>>(out, ln2, mlp, H_);
  gate_k<<<S_, 256, 0, stream>>>(mlp, wg, probs);

  // fc1: hbuf[s][e*1408+i] = silu(mlp @ fc1_w[e]^T) * probs[s][e]
  if (cw) gemm_bt<EPI_SILU, bf16, 128><<<dim3(11,16,8), 256, 0, stream>>>(
      mlp, fc1b, hbuf, probs, S_, INTER_, H_, H_, H_, EXP_*INTER_,
      0, (long)INTER_*H_, INTER_, 1, 8, 0, 0, 0);
  else    gemm_bt<EPI_SILU, float, 128><<<dim3(11,16,8), 256, 0, stream>>>(
      mlp, wfc1, hbuf, probs, S_, INTER_, H_, H_, H_, EXP_*INTER_,
      0, (long)INTER_*H_, INTER_, 1, 8, 0, 0, 0);

  // fc2: split-K z=8 (1 expert each), atomicAdd fp32 into out
  if (cw) gemm_bt<EPI_ATOM, bf16, 128><<<dim3(16,16,8), 256, 0, stream>>>(
      hbuf, fc2b, out, hidden, S_, H_, INTER_, EXP_*INTER_, 0, H_,
      (long)INTER_, 0, 0, 0, 0, INTER_, (long)H_*INTER_, 1);
  else    gemm_bt<EPI_ATOM, float, 128><<<dim3(16,16,8), 256, 0, stream>>>(
      hbuf, wfc2, out, hidden, S_, H_, INTER_, EXP_*INTER_, 0, H_,
      (long)INTER_, 0, 0, 0, 0, INTER_, (long)H_*INTER_, 1);
}